// Round 2
// baseline (118.758 us; speedup 1.0000x reference)
//
#include <hip/hip_runtime.h>
#include <hip/hip_bf16.h>

// out[b][n] = x[b][n] * |W[n][n]|   (BATCH=65536, N=1024, f32)
// Memory-bound elementwise column scale.
// v2: 4x unrolled float4 stream + nontemporal load/store for max MLP
//     and zero cache pollution (512 MiB streamed, no reuse).

#define N_COLS 1024
#define BLOCK 256

typedef float v4f __attribute__((ext_vector_type(4)));

__global__ __launch_bounds__(BLOCK) void diag_scale_kernel(
    const float* __restrict__ x,
    const float* __restrict__ W,
    float* __restrict__ out,
    int n_f4)   // total float4 elements = BATCH*N/4
{
    const int t = threadIdx.x;          // 0..255
    const int c0 = t * 4;               // this thread's first column

    // Diagonal: W[c][c] at flat c*1025. Tiny, L2-resident after first touch.
    v4f w;
    w.x = fabsf(W[(size_t)(c0 + 0) * (N_COLS + 1)]);
    w.y = fabsf(W[(size_t)(c0 + 1) * (N_COLS + 1)]);
    w.z = fabsf(W[(size_t)(c0 + 2) * (N_COLS + 1)]);
    w.w = fabsf(W[(size_t)(c0 + 3) * (N_COLS + 1)]);

    const v4f* __restrict__ xv = reinterpret_cast<const v4f*>(x);
    v4f* __restrict__ ov = reinterpret_cast<v4f*>(out);

    // stride is a multiple of BLOCK (=256 = f4 per row), so each thread's
    // flat index mod 256 == t always -> column set invariant across iters.
    const size_t stride = (size_t)gridDim.x * BLOCK;
    size_t i = (size_t)blockIdx.x * BLOCK + t;

    // Main: 4 independent loads in flight before any store.
    for (; i + 3 * stride < (size_t)n_f4; i += 4 * stride) {
        v4f a = __builtin_nontemporal_load(xv + i);
        v4f b = __builtin_nontemporal_load(xv + i + stride);
        v4f c = __builtin_nontemporal_load(xv + i + 2 * stride);
        v4f d = __builtin_nontemporal_load(xv + i + 3 * stride);
        a *= w; b *= w; c *= w; d *= w;
        __builtin_nontemporal_store(a, ov + i);
        __builtin_nontemporal_store(b, ov + i + stride);
        __builtin_nontemporal_store(c, ov + i + 2 * stride);
        __builtin_nontemporal_store(d, ov + i + 3 * stride);
    }
    // Tail (empty for 65536x1024 with grid=2048, kept for safety).
    for (; i < (size_t)n_f4; i += stride) {
        v4f a = __builtin_nontemporal_load(xv + i);
        a *= w;
        __builtin_nontemporal_store(a, ov + i);
    }
}

extern "C" void kernel_launch(void* const* d_in, const int* in_sizes, int n_in,
                              void* d_out, int out_size, void* d_ws, size_t ws_size,
                              hipStream_t stream)
{
    const float* x = (const float*)d_in[0];   // [BATCH, N]
    const float* W = (const float*)d_in[1];   // [N, N]
    float* out = (float*)d_out;               // [BATCH, N]

    const int n_f4 = in_sizes[0] / 4;         // 16,777,216

    const int grid = 2048;                    // 8 blocks/CU * 256 CU
    diag_scale_kernel<<<grid, BLOCK, 0, stream>>>(x, W, out, n_f4);
}

// Round 3
// 97.620 us; speedup vs baseline: 1.2165x; 1.2165x over previous
//
#include <hip/hip_runtime.h>
#include <hip/hip_bf16.h>

// out[b][n] = x[b][n] * |W[n][n]|   (BATCH=65536, N=1024, f32)
// v3: two-phase. Phase 1: gather |diag(W)| -> d_ws (4 KB). Phase 2: pure
// copy-shaped one-shot kernel, one row per block, coalesced w load from ws.

#define N_COLS 1024
#define BLOCK 256

typedef float v4f __attribute__((ext_vector_type(4)));

__global__ __launch_bounds__(BLOCK) void gather_diag_kernel(
    const float* __restrict__ W,
    float* __restrict__ ws)
{
    const int t = threadIdx.x;      // 0..255, handles columns 4t..4t+3
    v4f w;
    w.x = fabsf(W[(size_t)(4 * t + 0) * (N_COLS + 1)]);
    w.y = fabsf(W[(size_t)(4 * t + 1) * (N_COLS + 1)]);
    w.z = fabsf(W[(size_t)(4 * t + 2) * (N_COLS + 1)]);
    w.w = fabsf(W[(size_t)(4 * t + 3) * (N_COLS + 1)]);
    reinterpret_cast<v4f*>(ws)[t] = w;
}

__global__ __launch_bounds__(BLOCK) void diag_scale_kernel(
    const float* __restrict__ x,
    const float* __restrict__ ws,   // |diag(W)|, 1024 floats, L2-resident
    float* __restrict__ out)
{
    const int t = threadIdx.x;                      // f4 column 0..255
    const v4f w = reinterpret_cast<const v4f*>(ws)[t];  // coalesced, L2 hit

    const size_t idx = (size_t)blockIdx.x * (N_COLS / 4) + t;  // one row/block
    v4f v = reinterpret_cast<const v4f*>(x)[idx];
    v *= w;
    reinterpret_cast<v4f*>(out)[idx] = v;
}

extern "C" void kernel_launch(void* const* d_in, const int* in_sizes, int n_in,
                              void* d_out, int out_size, void* d_ws, size_t ws_size,
                              hipStream_t stream)
{
    const float* x = (const float*)d_in[0];   // [BATCH, N]
    const float* W = (const float*)d_in[1];   // [N, N]
    float* out = (float*)d_out;               // [BATCH, N]
    float* ws = (float*)d_ws;                 // >= 4 KB scratch

    const int rows = in_sizes[0] / N_COLS;    // 65536

    gather_diag_kernel<<<1, BLOCK, 0, stream>>>(W, ws);
    diag_scale_kernel<<<rows, BLOCK, 0, stream>>>(x, ws, out);
}

// Round 4
// 93.485 us; speedup vs baseline: 1.2703x; 1.0442x over previous
//
#include <hip/hip_runtime.h>
#include <hip/hip_bf16.h>

// out[b][n] = x[b][n] * |W[n][n]|   (BATCH=65536, N=1024, f32)
// v4: gather diag -> ws; then copy-shaped kernel, 4 rows per block,
// 4 independent float4 streams per thread, nontemporal x/out.

#define N_COLS 1024
#define BLOCK 256
#define ROWS_PER_BLOCK 4

typedef float v4f __attribute__((ext_vector_type(4)));

__global__ __launch_bounds__(BLOCK) void gather_diag_kernel(
    const float* __restrict__ W,
    float* __restrict__ ws)
{
    const int t = threadIdx.x;      // 0..255, columns 4t..4t+3
    v4f w;
    w.x = fabsf(W[(size_t)(4 * t + 0) * (N_COLS + 1)]);
    w.y = fabsf(W[(size_t)(4 * t + 1) * (N_COLS + 1)]);
    w.z = fabsf(W[(size_t)(4 * t + 2) * (N_COLS + 1)]);
    w.w = fabsf(W[(size_t)(4 * t + 3) * (N_COLS + 1)]);
    reinterpret_cast<v4f*>(ws)[t] = w;
}

__global__ __launch_bounds__(BLOCK) void diag_scale_kernel(
    const float* __restrict__ x,
    const float* __restrict__ ws,   // |diag(W)|, 1024 floats, L2-resident
    float* __restrict__ out)
{
    const int t = threadIdx.x;                          // f4 column 0..255
    const v4f w = reinterpret_cast<const v4f*>(ws)[t];  // cached, coalesced

    const int row_f4 = N_COLS / 4;                      // 256
    const size_t base = (size_t)blockIdx.x * (ROWS_PER_BLOCK * row_f4) + t;

    const v4f* __restrict__ xv = reinterpret_cast<const v4f*>(x);
    v4f* __restrict__ ov = reinterpret_cast<v4f*>(out);

    // 4 independent loads in flight, then 4 stores. Same w for all
    // (thread t owns f4-column t in each of the 4 consecutive rows).
    v4f a = __builtin_nontemporal_load(xv + base);
    v4f b = __builtin_nontemporal_load(xv + base + row_f4);
    v4f c = __builtin_nontemporal_load(xv + base + 2 * row_f4);
    v4f d = __builtin_nontemporal_load(xv + base + 3 * row_f4);
    a *= w; b *= w; c *= w; d *= w;
    __builtin_nontemporal_store(a, ov + base);
    __builtin_nontemporal_store(b, ov + base + row_f4);
    __builtin_nontemporal_store(c, ov + base + 2 * row_f4);
    __builtin_nontemporal_store(d, ov + base + 3 * row_f4);
}

extern "C" void kernel_launch(void* const* d_in, const int* in_sizes, int n_in,
                              void* d_out, int out_size, void* d_ws, size_t ws_size,
                              hipStream_t stream)
{
    const float* x = (const float*)d_in[0];   // [BATCH, N]
    const float* W = (const float*)d_in[1];   // [N, N]
    float* out = (float*)d_out;               // [BATCH, N]
    float* ws = (float*)d_ws;                 // >= 4 KB scratch

    const int rows = in_sizes[0] / N_COLS;    // 65536
    const int grid = rows / ROWS_PER_BLOCK;   // 16384

    gather_diag_kernel<<<1, BLOCK, 0, stream>>>(W, ws);
    diag_scale_kernel<<<grid, BLOCK, 0, stream>>>(x, ws, out);
}